// Round 1
// baseline (201.394 us; speedup 1.0000x reference)
//
#include <hip/hip_runtime.h>

#define BLOCK 256
#define GRID  1024
#define B_ROWS 131072
#define C_COLS 128
#define K_SEL  64

// ws layout: acc[0] = total (double), acc[1] = masked-row count (double)
__global__ void init_acc(double* acc) {
    acc[0] = 0.0;
    acc[1] = 0.0;
}

__global__ __launch_bounds__(BLOCK) void semi_loss_main(
    const float* __restrict__ out,
    const float* __restrict__ outc,
    const float* __restrict__ lab,
    const int*  __restrict__ class_idx,
    const int*  __restrict__ batch_mask,
    double* __restrict__ acc)
{
    // Build per-column weight table: w[c] = multiplicity of c in class_idx.
    __shared__ float w[C_COLS];
    if (threadIdx.x < C_COLS) w[threadIdx.x] = 0.0f;
    __syncthreads();
    if (threadIdx.x < K_SEL) {
        int c = class_idx[threadIdx.x];
        atomicAdd(&w[c], 1.0f);
    }
    __syncthreads();

    const int total_vec = B_ROWS * C_COLS / 4;  // float4 elements
    float sum  = 0.0f;
    float cntf = 0.0f;

    int tid    = blockIdx.x * BLOCK + threadIdx.x;
    int stride = GRID * BLOCK;

    for (int v = tid; v < total_vec; v += stride) {
        int base = v << 2;              // first scalar element index
        int row  = base >> 7;           // /128
        int col  = base & (C_COLS - 1); // %128
        int m    = batch_mask[row];     // 32 lanes share a row -> broadcast
        if (col == 0) cntf += m ? 1.0f : 0.0f;
        if (!m) continue;               // skip masked rows: saves HBM traffic

        float4 o4  = ((const float4*)out )[v];
        float4 oc4 = ((const float4*)outc)[v];
        float4 y4  = ((const float4*)lab )[v];

        float ov[4]  = {o4.x,  o4.y,  o4.z,  o4.w};
        float ocv[4] = {oc4.x, oc4.y, oc4.z, oc4.w};
        float yv[4]  = {y4.x,  y4.y,  y4.z,  y4.w};

        #pragma unroll
        for (int j = 0; j < 4; ++j) {
            float wc = w[col + j];
            float o  = ov[j];
            float oc = ocv[j];
            float y  = yv[j];

            // sharp = o>0.5 ? o + (1-o)/4 : o - o/4
            float sharp = (o > 0.5f) ? (o + (1.0f - o) * 0.25f)
                                     : (o - o * 0.25f);
            // bce = -(y*max(log o,-100) + (1-y)*max(log(1-o),-100))
            float lo  = fmaxf(logf(o),        -100.0f);
            float l1o = fmaxf(logf(1.0f - o), -100.0f);
            float bce = -(y * lo + (1.0f - y) * l1o);

            float dp = o  - sharp;
            float dc = oc - sharp;
            float per_elem = bce + dp * dp + dc * dc;
            sum += wc * per_elem;
        }
    }

    // wave (64-lane) shuffle reduction
    #pragma unroll
    for (int off = 32; off > 0; off >>= 1) {
        sum  += __shfl_down(sum,  off);
        cntf += __shfl_down(cntf, off);
    }
    __shared__ float ssum[BLOCK / 64];
    __shared__ float scnt[BLOCK / 64];
    int wave = threadIdx.x >> 6;
    int lane = threadIdx.x & 63;
    if (lane == 0) { ssum[wave] = sum; scnt[wave] = cntf; }
    __syncthreads();
    if (threadIdx.x == 0) {
        float s = 0.0f, c = 0.0f;
        #pragma unroll
        for (int i = 0; i < BLOCK / 64; ++i) { s += ssum[i]; c += scnt[i]; }
        atomicAdd(&acc[0], (double)s);
        atomicAdd(&acc[1], (double)c);
    }
}

__global__ void finalize_kernel(const double* acc, float* out) {
    double cnt = acc[1] * (double)K_SEL;
    out[0] = (float)(acc[0] / cnt);
}

extern "C" void kernel_launch(void* const* d_in, const int* in_sizes, int n_in,
                              void* d_out, int out_size, void* d_ws, size_t ws_size,
                              hipStream_t stream) {
    const float* out_p  = (const float*)d_in[0];
    const float* outc_p = (const float*)d_in[1];
    const float* lab_p  = (const float*)d_in[2];
    const int*   cidx_p = (const int*)d_in[3];
    const int*   mask_p = (const int*)d_in[4];
    double* acc = (double*)d_ws;

    init_acc<<<1, 1, 0, stream>>>(acc);
    semi_loss_main<<<GRID, BLOCK, 0, stream>>>(out_p, outc_p, lab_p, cidx_p, mask_p, acc);
    finalize_kernel<<<1, 1, 0, stream>>>(acc, (float*)d_out);
}

// Round 2
// 194.384 us; speedup vs baseline: 1.0361x; 1.0361x over previous
//
#include <hip/hip_runtime.h>

#define BLOCK  256
#define B_ROWS 131072
#define C_COLS 128
#define K_SEL  64
// one float4 per thread per array: total float4 = B*C/4 = 4,194,304
#define TOTAL_VEC (B_ROWS * C_COLS / 4)
#define GRID (TOTAL_VEC / BLOCK)   // 16384 blocks, exact cover

// d_ws layout: float2 partials[GRID]  (x = sum, y = masked-row count)

__global__ __launch_bounds__(BLOCK) void semi_loss_main(
    const float* __restrict__ out,
    const float* __restrict__ outc,
    const float* __restrict__ lab,
    const int*  __restrict__ class_idx,
    const int*  __restrict__ batch_mask,
    float2* __restrict__ partials)
{
    // Per-column weight table: w[c] = multiplicity of c in class_idx.
    __shared__ float w[C_COLS];
    if (threadIdx.x < C_COLS) w[threadIdx.x] = 0.0f;
    __syncthreads();
    if (threadIdx.x < K_SEL) {
        int c = class_idx[threadIdx.x];
        atomicAdd(&w[c], 1.0f);
    }
    __syncthreads();

    const int v   = blockIdx.x * BLOCK + threadIdx.x; // float4 index
    const int row = v >> 5;          // 32 float4 per row
    const int c4  = v & 31;          // float4 index within row
    const int col = c4 << 2;         // first scalar col

    const int m = batch_mask[row];   // 32 lanes share a row (L1 broadcast)

    float sum  = 0.0f;
    float cntf = (c4 == 0 && m) ? 1.0f : 0.0f;

    if (m) {
        float4 o4  = ((const float4*)out )[v];
        float4 oc4 = ((const float4*)outc)[v];
        float4 y4  = ((const float4*)lab )[v];

        float ov[4]  = {o4.x,  o4.y,  o4.z,  o4.w};
        float ocv[4] = {oc4.x, oc4.y, oc4.z, oc4.w};
        float yv[4]  = {y4.x,  y4.y,  y4.z,  y4.w};

        #pragma unroll
        for (int j = 0; j < 4; ++j) {
            float wc = w[col + j];
            float o  = ov[j];
            float oc = ocv[j];
            float y  = yv[j];

            float sharp = (o > 0.5f) ? (o + (1.0f - o) * 0.25f)
                                     : (o - o * 0.25f);
            float lo  = fmaxf(logf(o),        -100.0f);
            float l1o = fmaxf(logf(1.0f - o), -100.0f);
            float bce = -(y * lo + (1.0f - y) * l1o);

            float dp = o  - sharp;
            float dc = oc - sharp;
            sum += wc * (bce + dp * dp + dc * dc);
        }
    }

    // wave (64) shuffle reduction, then LDS across the block's 4 waves
    #pragma unroll
    for (int off = 32; off > 0; off >>= 1) {
        sum  += __shfl_down(sum,  off);
        cntf += __shfl_down(cntf, off);
    }
    __shared__ float ssum[BLOCK / 64];
    __shared__ float scnt[BLOCK / 64];
    int wave = threadIdx.x >> 6;
    int lane = threadIdx.x & 63;
    if (lane == 0) { ssum[wave] = sum; scnt[wave] = cntf; }
    __syncthreads();
    if (threadIdx.x == 0) {
        float s = 0.0f, c = 0.0f;
        #pragma unroll
        for (int i = 0; i < BLOCK / 64; ++i) { s += ssum[i]; c += scnt[i]; }
        partials[blockIdx.x] = make_float2(s, c);
    }
}

__global__ __launch_bounds__(BLOCK) void semi_loss_reduce(
    const float2* __restrict__ partials, float* __restrict__ out)
{
    double s = 0.0, c = 0.0;
    for (int i = threadIdx.x; i < GRID; i += BLOCK) {
        float2 p = partials[i];
        s += (double)p.x;
        c += (double)p.y;
    }
    #pragma unroll
    for (int off = 32; off > 0; off >>= 1) {
        s += __shfl_down(s, off);
        c += __shfl_down(c, off);
    }
    __shared__ double dsum[BLOCK / 64];
    __shared__ double dcnt[BLOCK / 64];
    int wave = threadIdx.x >> 6;
    int lane = threadIdx.x & 63;
    if (lane == 0) { dsum[wave] = s; dcnt[wave] = c; }
    __syncthreads();
    if (threadIdx.x == 0) {
        double ts = 0.0, tc = 0.0;
        #pragma unroll
        for (int i = 0; i < BLOCK / 64; ++i) { ts += dsum[i]; tc += dcnt[i]; }
        out[0] = (float)(ts / (tc * (double)K_SEL));
    }
}

extern "C" void kernel_launch(void* const* d_in, const int* in_sizes, int n_in,
                              void* d_out, int out_size, void* d_ws, size_t ws_size,
                              hipStream_t stream) {
    const float* out_p  = (const float*)d_in[0];
    const float* outc_p = (const float*)d_in[1];
    const float* lab_p  = (const float*)d_in[2];
    const int*   cidx_p = (const int*)d_in[3];
    const int*   mask_p = (const int*)d_in[4];
    float2* partials = (float2*)d_ws;   // 16384 * 8 B = 128 KB scratch

    semi_loss_main<<<GRID, BLOCK, 0, stream>>>(out_p, outc_p, lab_p,
                                               cidx_p, mask_p, partials);
    semi_loss_reduce<<<1, BLOCK, 0, stream>>>(partials, (float*)d_out);
}